// Round 6
// baseline (158.785 us; speedup 1.0000x reference)
//
#include <hip/hip_runtime.h>
#include <hip/hip_bf16.h>

// Problem constants
#define B_    8
#define CIN   128
#define H_    64
#define W_    64
#define COUT  128
#define K_    16
#define HO    61
#define WO    61
#define HW_   (HO * WO)          // 3721

typedef short bf16x8 __attribute__((ext_vector_type(8)));
typedef short s16x4  __attribute__((ext_vector_type(4)));
typedef float f32x4  __attribute__((ext_vector_type(4)));
typedef float f32x4u __attribute__((ext_vector_type(4), aligned(4)));

#define B2F(s) __uint_as_float(((unsigned int)(unsigned short)(s)) << 16)

// ---------------------------------------------------------------------------
// Fused prep: blocks 0..511 transpose input [b][c][y][x] f32 -> T[b][y*64+x][c]
// bf16 (1 MB/batch, XCD-L2 resident); blocks 512..639 repack weight.
// Weight layout (fragment-major, pre-flipped, kk = k*128 + c):
//   A2[((blk*64 + it)*64 + lane)*8 + j];  o = blk*16 + (lane&15);
//   kk = it*32 + (lane>>4)*8 + j;  k = kk>>7;  c = kk&127.
__global__ __launch_bounds__(256) void prep_all(const float* __restrict__ inp,
                                                const float* __restrict__ w,
                                                __hip_bfloat16* __restrict__ T,
                                                __hip_bfloat16* __restrict__ A2) {
    const int t = threadIdx.x;
    if (blockIdx.x < 512) {
        __shared__ float ld[64][129];      // pad 129: conflict-free both phases
        const int b  = blockIdx.x >> 6;
        const int sb = (blockIdx.x & 63) << 6;   // 64-spatial slab
        const float* src = inp + ((size_t)b << 19);
        #pragma unroll
        for (int i = 0; i < 8; ++i) {
            int j  = i * 256 + t;
            int c  = j >> 4;
            int s4 = (j & 15) << 2;
            f32x4u v = *(const f32x4u*)(const void*)(src + ((size_t)c << 12) + sb + s4);
            #pragma unroll
            for (int q = 0; q < 4; ++q) ld[s4 + q][c] = v[q];
        }
        __syncthreads();
        __hip_bfloat16* dst = T + (((size_t)b << 12) + sb) * 128;
        #pragma unroll
        for (int i = 0; i < 8; ++i) {
            int j  = i * 256 + t;
            int s  = j >> 5;
            int c4 = (j & 31) << 2;
            s16x4 v;
            #pragma unroll
            for (int q = 0; q < 4; ++q) {
                __hip_bfloat16 hh = __float2bfloat16(ld[s][c4 + q]);
                v[q] = *reinterpret_cast<const short*>(&hh);
            }
            *(s16x4*)(void*)(dst + (size_t)s * 128 + c4) = v;
        }
    } else {
        int gid  = (blockIdx.x - 512) * 256 + t;   // 32768 threads
        int lane = gid & 63;
        int it   = (gid >> 6) & 63;
        int blk  = gid >> 12;
        int o    = blk * 16 + (lane & 15);
        int kk   = it * 32 + (lane >> 4) * 8;      // never crosses c=128
        int k    = kk >> 7;
        int c0   = kk & 127;
        const float* srcw = w + (((size_t)(o << 7) + c0) << 4) + (15 - k);
        __hip_bfloat16* dst = A2 + (size_t)gid * 8;
        #pragma unroll
        for (int j = 0; j < 8; ++j)
            dst[j] = __float2bfloat16(srcw[j << 4]);   // c = c0+j, same k
    }
}

// ---------------------------------------------------------------------------
// Main: block = 32 pixels x 128 couts, 4 waves (A-stream amortized over 2x
// pixels vs round-5).  Each wave: 2 cout-blocks x 2 px-groups; A-fragments
// loaded once per half and reused for both px-groups.  bf16 channel-last
// gather (1 fully-used 64B line per pair-corner) -> swizzled Bs ring ->
// MFMA.  loadA is issued AFTER the MFMA that frees avR, so its latency is
// covered by combine+barrier+next-gathers.  9 barriers/block.
__global__ __launch_bounds__(256, 3) void deform_gather(
        const __hip_bfloat16* __restrict__ T, const float* __restrict__ off,
        const float* __restrict__ msk, const __hip_bfloat16* __restrict__ A2,
        const float* __restrict__ bias, float* __restrict__ out) {

    __shared__ __align__(16) __hip_bfloat16 Bs[2][32 * 256];  // 2 x 16 KB
    __shared__ float pw[4][512];                              // bilinear weights
    __shared__ int   pb[2][512];                              // T elem offsets

    const int t   = threadIdx.x;
    const int bid = blockIdx.x;
    const int b   = bid & 7;               // batch<->XCD pinning (976 % 8 == 0)
    const int g   = bid >> 3;
    const int ho  = g >> 1;
    const int wt  = (g & 1) << 5;          // 0 or 32

    // ---- phase 0: exact per-(pixel,tap) bilinear params -> LDS (512 pairs) ----
    #pragma unroll
    for (int ii = 0; ii < 2; ++ii) {
        const int idx = ii * 256 + t;
        const int px  = idx & 31;
        const int k   = idx >> 5;
        const int wo  = wt + px;
        const bool pvalid = (wo < WO);
        const int wo_c = pvalid ? wo : (WO - 1);
        const int r    = ho * WO + wo_c;
        const int ki = k >> 2, kj = k & 3;
        const size_t offb = (size_t)b * (2 * K_ * HW_);
        float dy = off[offb + (size_t)(2 * k)     * HW_ + r];
        float dx = off[offb + (size_t)(2 * k + 1) * HW_ + r];
        float mm = msk[(size_t)b * (K_ * HW_) + (size_t)k * HW_ + r];
        if (!pvalid) mm = 0.0f;

        float y   = dy + (float)(ki + ho);
        float x   = dx + (float)(kj + wo_c);
        float y0f = floorf(y), x0f = floorf(x);
        float wy  = y - y0f,   wx  = x - x0f;
        int y0 = (int)y0f, x0 = (int)x0f;
        int y1 = y0 + 1,   x1 = x0 + 1;

        float wy0v = (1.0f - wy) * ((y0 >= 0 && y0 < H_) ? mm : 0.0f);
        float wy1v = wy          * ((y1 >= 0 && y1 < H_) ? mm : 0.0f);
        int cy0 = min(max(y0, 0), H_ - 1), cy1 = min(max(y1, 0), H_ - 1);

        float wx0v = (1.0f - wx) * ((x0 >= 0 && x0 < W_) ? 1.0f : 0.0f);
        float wx1v = wx          * ((x1 >= 0 && x1 < W_) ? 1.0f : 0.0f);
        int xb = min(max(x0, 0), W_ - 2);
        int tsh = x0 - xb;                 // -1,0,1 (else both x-weights 0)
        float a0 = (tsh == 0) ? wx0v : ((tsh == -1) ? wx1v : 0.0f);
        float a1 = (tsh == 0) ? wx1v : ((tsh ==  1) ? wx0v : 0.0f);

        pw[0][idx] = wy0v * a0;  pw[1][idx] = wy0v * a1;
        pw[2][idx] = wy1v * a0;  pw[3][idx] = wy1v * a1;
        pb[0][idx] = (cy0 * W_ + xb) << 7; // *128 channels (bf16 elems)
        pb[1][idx] = (cy1 * W_ + xb) << 7;
    }
    __syncthreads();

    const int lane = t & 63;
    const int wv   = t >> 6;
    const int p_g  = lane >> 2;            // gather pair-pixel within px-group
    const int cg_l = (lane & 3) << 3;      // 8-ch sub-slice within 32-group
    const int mrow = lane & 15;            // MFMA pixel col
    const int quad = lane >> 4;
    const __hip_bfloat16* Tb = T + ((size_t)b << 19);
    const int blk0 = 2 * wv, blk1 = 2 * wv + 1;

    // this wave's 4 gather units per half: u = wv*4 + i
    int tpar[4], cbU[4], pgU[4];
    #pragma unroll
    for (int i = 0; i < 4; ++i) {
        const int u = (wv << 2) + i;
        tpar[i] = u >> 3;                  // tap parity within half
        cbU[i]  = ((((u >> 1) & 3)) << 5) + cg_l;   // channel base 0..127
        pgU[i]  = u & 1;                   // px-group
    }

    f32x4 acc00 = {0.f,0.f,0.f,0.f}, acc01 = {0.f,0.f,0.f,0.f};
    f32x4 acc10 = {0.f,0.f,0.f,0.f}, acc11 = {0.f,0.f,0.f,0.f};

    bf16x8 cU[4][4];                       // 4 units x 4 corners
    float  wtU[4][4];
    int    swzU[4];

    // gather 4 units for half h: 16 coalesced dwordx4 (one 64B line each)
    auto uget_all = [&](int h) {
        #pragma unroll
        for (int i = 0; i < 4; ++i) {
            const int tap  = 2 * h + tpar[i];
            const int pidx = (tap << 5) + (pgU[i] << 4) + p_g;
            wtU[i][0] = pw[0][pidx]; wtU[i][1] = pw[1][pidx];
            wtU[i][2] = pw[2][pidx]; wtU[i][3] = pw[3][pidx];
            const __hip_bfloat16* p0 = Tb + pb[0][pidx] + cbU[i];
            const __hip_bfloat16* p1 = Tb + pb[1][pidx] + cbU[i];
            cU[i][0] = *(const bf16x8*)(const void*)(p0);          // (y0,x0)
            cU[i][1] = *(const bf16x8*)(const void*)(p0 + 128);    // (y0,x1)
            cU[i][2] = *(const bf16x8*)(const void*)(p1);          // (y1,x0)
            cU[i][3] = *(const bf16x8*)(const void*)(p1 + 128);    // (y1,x1)
            const int kkl = (tpar[i] << 7) + cbU[i];
            const int row = (pgU[i] << 4) + p_g;
            swzU[i] = (row << 8) + ((kkl + (row << 3)) & 255);
        }
    };

    // combine (bf16 corners -> f32 bilinear -> bf16) -> 4 x ds_write_b128
    auto ucomb_all = [&](int hb) {
        #pragma unroll
        for (int i = 0; i < 4; ++i) {
            bf16x8 bbv;
            #pragma unroll
            for (int q = 0; q < 8; ++q) {
                float s = wtU[i][0] * B2F(cU[i][0][q]) + wtU[i][1] * B2F(cU[i][1][q])
                        + wtU[i][2] * B2F(cU[i][2][q]) + wtU[i][3] * B2F(cU[i][3][q]);
                __hip_bfloat16 hh = __float2bfloat16(s);
                bbv[q] = *reinterpret_cast<const short*>(&hh);
            }
            *(bf16x8*)(void*)(&Bs[hb][swzU[i]]) = bbv;
        }
    };

    // A-fragments for one half (16 x bf16x8); reused for both px-groups
    bf16x8 avR[16];
    auto loadA = [&](int hp) {
        const __hip_bfloat16* a0 = A2 + ((size_t)((blk0 * 64 + hp * 8) * 64 + lane) << 3);
        const __hip_bfloat16* a1 = A2 + ((size_t)((blk1 * 64 + hp * 8) * 64 + lane) << 3);
        #pragma unroll
        for (int s_ = 0; s_ < 8; ++s_) {
            avR[2 * s_]     = *(const bf16x8*)(const void*)(a0 + ((size_t)s_ << 9));
            avR[2 * s_ + 1] = *(const bf16x8*)(const void*)(a1 + ((size_t)s_ << 9));
        }
    };

    auto mfma_exec = [&](int hp) {
        const int hb = hp & 1;
        #pragma unroll
        for (int s_ = 0; s_ < 8; ++s_) {
            const int base = (s_ << 5) + (quad << 3);
            const int r0 = mrow;               // px-group 0 row
            const int r1 = 16 + mrow;          // px-group 1 row
            const int i0 = (r0 << 8) + ((base + (r0 << 3)) & 255);
            const int i1 = (r1 << 8) + ((base + (r1 << 3)) & 255);
            bf16x8 bb0 = *(const bf16x8*)(const void*)(&Bs[hb][i0]);
            bf16x8 bb1 = *(const bf16x8*)(const void*)(&Bs[hb][i1]);
            acc00 = __builtin_amdgcn_mfma_f32_16x16x32_bf16(avR[2*s_],   bb0, acc00, 0, 0, 0);
            acc01 = __builtin_amdgcn_mfma_f32_16x16x32_bf16(avR[2*s_],   bb1, acc01, 0, 0, 0);
            acc10 = __builtin_amdgcn_mfma_f32_16x16x32_bf16(avR[2*s_+1], bb0, acc10, 0, 0, 0);
            acc11 = __builtin_amdgcn_mfma_f32_16x16x32_bf16(avR[2*s_+1], bb1, acc11, 0, 0, 0);
        }
    };

    // prologue: half 0 (the one uncovered gather stall of the kernel)
    uget_all(0);
    ucomb_all(0);
    loadA(0);
    __syncthreads();

    #pragma unroll 1
    for (int h = 1; h < 8; ++h) {
        uget_all(h);                       // gathers for half h, issued first
        __builtin_amdgcn_s_setprio(1);
        mfma_exec(h - 1);                  // avR(h-1) covered since last iter
        __builtin_amdgcn_s_setprio(0);
        loadA(h);                          // reuses avR after MFMA frees it
        ucomb_all(h & 1);                  // gathers covered by the MFMA phase
        __syncthreads();                   // one barrier per half
    }
    mfma_exec(7);

    // ---- epilogue: C/D col = mrow (pixel), row = quad*4 + jj (cout) ----
    #pragma unroll
    for (int pg = 0; pg < 2; ++pg) {
        const int wo = wt + (pg << 4) + mrow;
        if (wo < WO) {
            const size_t outb = (size_t)b * (COUT * HW_) + (size_t)(ho * WO + wo);
            const f32x4 a0 = pg ? acc01 : acc00;
            const f32x4 a1 = pg ? acc11 : acc10;
            #pragma unroll
            for (int jj = 0; jj < 4; ++jj) {
                int o0 = blk0 * 16 + quad * 4 + jj;
                int o1 = blk1 * 16 + quad * 4 + jj;
                out[outb + (size_t)o0 * HW_] = a0[jj] + bias[o0];
                out[outb + (size_t)o1 * HW_] = a1[jj] + bias[o1];
            }
        }
    }
}

extern "C" void kernel_launch(void* const* d_in, const int* in_sizes, int n_in,
                              void* d_out, int out_size, void* d_ws, size_t ws_size,
                              hipStream_t stream) {
    const float* inp  = (const float*)d_in[0];
    const float* off  = (const float*)d_in[1];
    const float* msk  = (const float*)d_in[2];
    const float* wgt  = (const float*)d_in[3];
    const float* bias = (const float*)d_in[4];
    float* out = (float*)d_out;

    __hip_bfloat16* A2 = (__hip_bfloat16*)d_ws;                       // 512 KB
    __hip_bfloat16* T  = (__hip_bfloat16*)((char*)d_ws + (1 << 20));  // 8 MB

    prep_all<<<640, 256, 0, stream>>>(inp, wgt, T, A2);

    int nblk = B_ * HO * 2;                // 976, bid&7 = batch
    deform_gather<<<nblk, 256, 0, stream>>>(T, off, msk, A2, bias, out);
}

// Round 7
// 120.124 us; speedup vs baseline: 1.3218x; 1.3218x over previous
//
#include <hip/hip_runtime.h>
#include <hip/hip_bf16.h>

// Problem constants
#define B_    8
#define CIN   128
#define H_    64
#define W_    64
#define COUT  128
#define K_    16
#define HO    61
#define WO    61
#define HW_   (HO * WO)          // 3721

typedef short bf16x8 __attribute__((ext_vector_type(8)));
typedef short s16x4  __attribute__((ext_vector_type(4)));
typedef float f32x4  __attribute__((ext_vector_type(4)));
typedef float f32x4u __attribute__((ext_vector_type(4), aligned(4)));

#define B2F(s) __uint_as_float(((unsigned int)(unsigned short)(s)) << 16)

// ---------------------------------------------------------------------------
// Fused prep: blocks 0..511 transpose input [b][c][y][x] f32 -> T[b][y*64+x][c]
// bf16 (1 MB/batch, XCD-L2 resident); blocks 512..639 repack weight.
// Weight layout (fragment-major, pre-flipped, kk = k*128 + c):
//   A2[((blk*64 + it)*64 + lane)*8 + j];  o = blk*16 + (lane&15);
//   kk = it*32 + (lane>>4)*8 + j;  k = kk>>7;  c = kk&127.
__global__ __launch_bounds__(256) void prep_all(const float* __restrict__ inp,
                                                const float* __restrict__ w,
                                                __hip_bfloat16* __restrict__ T,
                                                __hip_bfloat16* __restrict__ A2) {
    const int t = threadIdx.x;
    if (blockIdx.x < 512) {
        __shared__ float ld[64][129];      // pad 129: conflict-free both phases
        const int b  = blockIdx.x >> 6;
        const int sb = (blockIdx.x & 63) << 6;   // 64-spatial slab
        const float* src = inp + ((size_t)b << 19);
        #pragma unroll
        for (int i = 0; i < 8; ++i) {
            int j  = i * 256 + t;
            int c  = j >> 4;
            int s4 = (j & 15) << 2;
            f32x4u v = *(const f32x4u*)(const void*)(src + ((size_t)c << 12) + sb + s4);
            #pragma unroll
            for (int q = 0; q < 4; ++q) ld[s4 + q][c] = v[q];
        }
        __syncthreads();
        __hip_bfloat16* dst = T + (((size_t)b << 12) + sb) * 128;
        #pragma unroll
        for (int i = 0; i < 8; ++i) {
            int j  = i * 256 + t;
            int s  = j >> 5;
            int c4 = (j & 31) << 2;
            s16x4 v;
            #pragma unroll
            for (int q = 0; q < 4; ++q) {
                __hip_bfloat16 hh = __float2bfloat16(ld[s][c4 + q]);
                v[q] = *reinterpret_cast<const short*>(&hh);
            }
            *(s16x4*)(void*)(dst + (size_t)s * 128 + c4) = v;
        }
    } else {
        int gid  = (blockIdx.x - 512) * 256 + t;   // 32768 threads
        int lane = gid & 63;
        int it   = (gid >> 6) & 63;
        int blk  = gid >> 12;
        int o    = blk * 16 + (lane & 15);
        int kk   = it * 32 + (lane >> 4) * 8;      // never crosses c=128
        int k    = kk >> 7;
        int c0   = kk & 127;
        const float* srcw = w + (((size_t)(o << 7) + c0) << 4) + (15 - k);
        __hip_bfloat16* dst = A2 + (size_t)gid * 8;
        #pragma unroll
        for (int j = 0; j < 8; ++j)
            dst[j] = __float2bfloat16(srcw[j << 4]);   // c = c0+j, same k
    }
}

// ---------------------------------------------------------------------------
// Main: block = 32 pixels x 128 couts, 4 waves.  A-stream amortized over 2
// px-groups (each A-fragment feeds 2 MFMAs).  QUARTER-phase pipeline: one tap
// (128 kk) per phase, 16 phases; per phase per wave only 2 gather units
// (cU = 32 VGPR) + 8 A-frags (avR = 32 VGPR) are live -> no spills (the
// round-6 failure: 64+64 live regs -> scratch = 3x HBM traffic).
// LDS 28 KB -> 4-5 blocks/CU.  kk order identical to round 5 -> same absmax.
__global__ __launch_bounds__(256, 3) void deform_gather(
        const __hip_bfloat16* __restrict__ T, const float* __restrict__ off,
        const float* __restrict__ msk, const __hip_bfloat16* __restrict__ A2,
        const float* __restrict__ bias, float* __restrict__ out) {

    __shared__ __align__(16) __hip_bfloat16 Bs[2][32 * 128];  // 2 x 8 KB
    __shared__ float pw[4][512];                              // bilinear weights
    __shared__ int   pb[2][512];                              // T elem offsets

    const int t   = threadIdx.x;
    const int bid = blockIdx.x;
    const int b   = bid & 7;               // batch<->XCD pinning (976 % 8 == 0)
    const int g   = bid >> 3;
    const int ho  = g >> 1;
    const int wt  = (g & 1) << 5;          // 0 or 32

    // ---- phase 0: exact per-(pixel,tap) bilinear params -> LDS (512 pairs) ----
    #pragma unroll
    for (int ii = 0; ii < 2; ++ii) {
        const int idx = ii * 256 + t;
        const int px  = idx & 31;
        const int k   = idx >> 5;
        const int wo  = wt + px;
        const bool pvalid = (wo < WO);
        const int wo_c = pvalid ? wo : (WO - 1);
        const int r    = ho * WO + wo_c;
        const int ki = k >> 2, kj = k & 3;
        const size_t offb = (size_t)b * (2 * K_ * HW_);
        float dy = off[offb + (size_t)(2 * k)     * HW_ + r];
        float dx = off[offb + (size_t)(2 * k + 1) * HW_ + r];
        float mm = msk[(size_t)b * (K_ * HW_) + (size_t)k * HW_ + r];
        if (!pvalid) mm = 0.0f;

        float y   = dy + (float)(ki + ho);
        float x   = dx + (float)(kj + wo_c);
        float y0f = floorf(y), x0f = floorf(x);
        float wy  = y - y0f,   wx  = x - x0f;
        int y0 = (int)y0f, x0 = (int)x0f;
        int y1 = y0 + 1,   x1 = x0 + 1;

        float wy0v = (1.0f - wy) * ((y0 >= 0 && y0 < H_) ? mm : 0.0f);
        float wy1v = wy          * ((y1 >= 0 && y1 < H_) ? mm : 0.0f);
        int cy0 = min(max(y0, 0), H_ - 1), cy1 = min(max(y1, 0), H_ - 1);

        float wx0v = (1.0f - wx) * ((x0 >= 0 && x0 < W_) ? 1.0f : 0.0f);
        float wx1v = wx          * ((x1 >= 0 && x1 < W_) ? 1.0f : 0.0f);
        int xb = min(max(x0, 0), W_ - 2);
        int tsh = x0 - xb;                 // -1,0,1 (else both x-weights 0)
        float a0 = (tsh == 0) ? wx0v : ((tsh == -1) ? wx1v : 0.0f);
        float a1 = (tsh == 0) ? wx1v : ((tsh ==  1) ? wx0v : 0.0f);

        pw[0][idx] = wy0v * a0;  pw[1][idx] = wy0v * a1;
        pw[2][idx] = wy1v * a0;  pw[3][idx] = wy1v * a1;
        pb[0][idx] = (cy0 * W_ + xb) << 7; // *128 channels (bf16 elems)
        pb[1][idx] = (cy1 * W_ + xb) << 7;
    }
    __syncthreads();

    const int lane = t & 63;
    const int wv   = t >> 6;
    const int p_g  = lane >> 2;            // gather pair-pixel within px-group
    const int cg_l = (lane & 3) << 3;      // 8-ch sub-slice
    const int mrow = lane & 15;            // MFMA pixel col
    const int quad = lane >> 4;
    const __hip_bfloat16* Tb = T + ((size_t)b << 19);
    const int blk0 = 2 * wv, blk1 = 2 * wv + 1;
    const int cb   = (wv << 5) + cg_l;     // this wave's fixed channel slice

    f32x4 acc00 = {0.f,0.f,0.f,0.f}, acc01 = {0.f,0.f,0.f,0.f};
    f32x4 acc10 = {0.f,0.f,0.f,0.f}, acc11 = {0.f,0.f,0.f,0.f};

    bf16x8 cU[2][4];                       // 2 units (px-groups) x 4 corners
    float  wtU[2][4];
    int    swzU[2];

    // gather 2 units for tap qp: 8 coalesced dwordx4 (one 64B line each)
    auto uget = [&](int qp) {
        #pragma unroll
        for (int i = 0; i < 2; ++i) {      // i = px-group
            const int pidx = (qp << 5) + (i << 4) + p_g;
            wtU[i][0] = pw[0][pidx]; wtU[i][1] = pw[1][pidx];
            wtU[i][2] = pw[2][pidx]; wtU[i][3] = pw[3][pidx];
            const __hip_bfloat16* p0 = Tb + pb[0][pidx] + cb;
            const __hip_bfloat16* p1 = Tb + pb[1][pidx] + cb;
            cU[i][0] = *(const bf16x8*)(const void*)(p0);          // (y0,x0)
            cU[i][1] = *(const bf16x8*)(const void*)(p0 + 128);    // (y0,x1)
            cU[i][2] = *(const bf16x8*)(const void*)(p1);          // (y1,x0)
            cU[i][3] = *(const bf16x8*)(const void*)(p1 + 128);    // (y1,x1)
            const int row = (i << 4) + p_g;
            swzU[i] = (row << 7) + ((cb + (row << 3)) & 127);
        }
    };

    // combine (bf16 corners -> f32 bilinear -> bf16) -> 2 x ds_write_b128
    auto ucomb = [&](int bb_) {
        #pragma unroll
        for (int i = 0; i < 2; ++i) {
            bf16x8 v;
            #pragma unroll
            for (int q = 0; q < 8; ++q) {
                float s = wtU[i][0] * B2F(cU[i][0][q]) + wtU[i][1] * B2F(cU[i][1][q])
                        + wtU[i][2] * B2F(cU[i][2][q]) + wtU[i][3] * B2F(cU[i][3][q]);
                __hip_bfloat16 hh = __float2bfloat16(s);
                v[q] = *reinterpret_cast<const short*>(&hh);
            }
            *(bf16x8*)(void*)(&Bs[bb_][swzU[i]]) = v;
        }
    };

    // A-fragments for one quarter (8 x bf16x8 = 32 VGPR)
    bf16x8 avR[8];
    auto loadA = [&](int qp) {
        #pragma unroll
        for (int s_ = 0; s_ < 4; ++s_) {
            const int it = qp * 4 + s_;
            avR[2*s_]   = *(const bf16x8*)(const void*)(
                A2 + ((size_t)((blk0 * 64 + it) * 64 + lane) << 3));
            avR[2*s_+1] = *(const bf16x8*)(const void*)(
                A2 + ((size_t)((blk1 * 64 + it) * 64 + lane) << 3));
        }
    };

    auto mfma_exec = [&](int qp) {
        const int bb_ = qp & 1;
        #pragma unroll
        for (int s_ = 0; s_ < 4; ++s_) {
            const int base = (s_ << 5) + (quad << 3);
            const int r0 = mrow;
            const int r1 = 16 + mrow;
            const int i0 = (r0 << 7) + ((base + (r0 << 3)) & 127);
            const int i1 = (r1 << 7) + ((base + (r1 << 3)) & 127);
            bf16x8 bb0 = *(const bf16x8*)(const void*)(&Bs[bb_][i0]);
            bf16x8 bb1 = *(const bf16x8*)(const void*)(&Bs[bb_][i1]);
            acc00 = __builtin_amdgcn_mfma_f32_16x16x32_bf16(avR[2*s_],   bb0, acc00, 0, 0, 0);
            acc01 = __builtin_amdgcn_mfma_f32_16x16x32_bf16(avR[2*s_],   bb1, acc01, 0, 0, 0);
            acc10 = __builtin_amdgcn_mfma_f32_16x16x32_bf16(avR[2*s_+1], bb0, acc10, 0, 0, 0);
            acc11 = __builtin_amdgcn_mfma_f32_16x16x32_bf16(avR[2*s_+1], bb1, acc11, 0, 0, 0);
        }
    };

    // prologue: tap 0 (the one uncovered gather stall)
    uget(0);
    ucomb(0);
    loadA(0);
    __syncthreads();

    #pragma unroll 1
    for (int qp = 1; qp < 16; ++qp) {
        uget(qp);                          // 8 gather loads, issued first
        __builtin_amdgcn_s_setprio(1);
        mfma_exec(qp - 1);                 // covers gather latency; avR ready
        __builtin_amdgcn_s_setprio(0);
        loadA(qp);                         // refills avR; covered to next phase
        ucomb(qp & 1);                     // waits gathers (already covered)
        __syncthreads();                   // one barrier per tap
    }
    mfma_exec(15);

    // ---- epilogue: C/D col = mrow (pixel), row = quad*4 + jj (cout) ----
    #pragma unroll
    for (int pg = 0; pg < 2; ++pg) {
        const int wo = wt + (pg << 4) + mrow;
        if (wo < WO) {
            const size_t outb = (size_t)b * (COUT * HW_) + (size_t)(ho * WO + wo);
            const f32x4 a0 = pg ? acc01 : acc00;
            const f32x4 a1 = pg ? acc11 : acc10;
            #pragma unroll
            for (int jj = 0; jj < 4; ++jj) {
                int o0 = blk0 * 16 + quad * 4 + jj;
                int o1 = blk1 * 16 + quad * 4 + jj;
                out[outb + (size_t)o0 * HW_] = a0[jj] + bias[o0];
                out[outb + (size_t)o1 * HW_] = a1[jj] + bias[o1];
            }
        }
    }
}

extern "C" void kernel_launch(void* const* d_in, const int* in_sizes, int n_in,
                              void* d_out, int out_size, void* d_ws, size_t ws_size,
                              hipStream_t stream) {
    const float* inp  = (const float*)d_in[0];
    const float* off  = (const float*)d_in[1];
    const float* msk  = (const float*)d_in[2];
    const float* wgt  = (const float*)d_in[3];
    const float* bias = (const float*)d_in[4];
    float* out = (float*)d_out;

    __hip_bfloat16* A2 = (__hip_bfloat16*)d_ws;                       // 512 KB
    __hip_bfloat16* T  = (__hip_bfloat16*)((char*)d_ws + (1 << 20));  // 8 MB

    prep_all<<<640, 256, 0, stream>>>(inp, wgt, T, A2);

    int nblk = B_ * HO * 2;                // 976, bid&7 = batch
    deform_gather<<<nblk, 256, 0, stream>>>(T, off, msk, A2, bias, out);
}

// Round 8
// 114.201 us; speedup vs baseline: 1.3904x; 1.0519x over previous
//
#include <hip/hip_runtime.h>
#include <hip/hip_bf16.h>

// Problem constants
#define B_    8
#define CIN   128
#define H_    64
#define W_    64
#define COUT  128
#define K_    16
#define HO    61
#define WO    61
#define HW_   (HO * WO)          // 3721

typedef short bf16x8 __attribute__((ext_vector_type(8)));
typedef short s16x4  __attribute__((ext_vector_type(4)));
typedef float f32x4  __attribute__((ext_vector_type(4)));
typedef float f32x4u __attribute__((ext_vector_type(4), aligned(4)));

#define B2F(s) __uint_as_float(((unsigned int)(unsigned short)(s)) << 16)

// ---------------------------------------------------------------------------
// Fused prep: blocks 0..511 transpose input [b][c][y][x] f32 -> T[b][y*64+x][c]
// bf16 (1 MB/batch, XCD-L2 resident); blocks 512..639 repack weight.
// Weight layout (fragment-major, pre-flipped, kk = k*128 + c):
//   A2[((blk*64 + it)*64 + lane)*8 + j];  o = blk*16 + (lane&15);
//   kk = it*32 + (lane>>4)*8 + j;  k = kk>>7;  c = kk&127.
__global__ __launch_bounds__(256) void prep_all(const float* __restrict__ inp,
                                                const float* __restrict__ w,
                                                __hip_bfloat16* __restrict__ T,
                                                __hip_bfloat16* __restrict__ A2) {
    const int t = threadIdx.x;
    if (blockIdx.x < 512) {
        __shared__ float ld[64][129];      // pad 129: conflict-free both phases
        const int b  = blockIdx.x >> 6;
        const int sb = (blockIdx.x & 63) << 6;   // 64-spatial slab
        const float* src = inp + ((size_t)b << 19);
        #pragma unroll
        for (int i = 0; i < 8; ++i) {
            int j  = i * 256 + t;
            int c  = j >> 4;
            int s4 = (j & 15) << 2;
            f32x4u v = *(const f32x4u*)(const void*)(src + ((size_t)c << 12) + sb + s4);
            #pragma unroll
            for (int q = 0; q < 4; ++q) ld[s4 + q][c] = v[q];
        }
        __syncthreads();
        __hip_bfloat16* dst = T + (((size_t)b << 12) + sb) * 128;
        #pragma unroll
        for (int i = 0; i < 8; ++i) {
            int j  = i * 256 + t;
            int s  = j >> 5;
            int c4 = (j & 31) << 2;
            s16x4 v;
            #pragma unroll
            for (int q = 0; q < 4; ++q) {
                __hip_bfloat16 hh = __float2bfloat16(ld[s][c4 + q]);
                v[q] = *reinterpret_cast<const short*>(&hh);
            }
            *(s16x4*)(void*)(dst + (size_t)s * 128 + c4) = v;
        }
    } else {
        int gid  = (blockIdx.x - 512) * 256 + t;   // 32768 threads
        int lane = gid & 63;
        int it   = (gid >> 6) & 63;
        int blk  = gid >> 12;
        int o    = blk * 16 + (lane & 15);
        int kk   = it * 32 + (lane >> 4) * 8;      // never crosses c=128
        int k    = kk >> 7;
        int c0   = kk & 127;
        const float* srcw = w + (((size_t)(o << 7) + c0) << 4) + (15 - k);
        __hip_bfloat16* dst = A2 + (size_t)gid * 8;
        #pragma unroll
        for (int j = 0; j < 8; ++j)
            dst[j] = __float2bfloat16(srcw[j << 4]);   // c = c0+j, same k
    }
}

// ---------------------------------------------------------------------------
// Main: block = ONE OUTPUT ROW (64 px incl. 3 pad) x 128 couts, 8 waves.
// Each wave owns one 16-cout block and all 4 px-groups: every A-fragment
// feeds 4 MFMAs (A line-traffic per pixel halves vs round 7).  Quarter-phase
// pipeline (one tap = 128 kk per phase, 16 phases); per wave per phase:
// 2 gather units (cU=32 VGPR) + 4 A-frags (16 VGPR) + 4 acc (16) ~= 100 VGPR
// -> forced <=128 via launch_bounds, no spills (round-6 ledger check).
// LDS 56 KB -> 2 blocks/CU (matches 488/256 = 1.9 grid).  kk order identical
// to rounds 5-7 -> absmax bit-identical.
__global__ __launch_bounds__(512, 4) void deform_gather(
        const __hip_bfloat16* __restrict__ T, const float* __restrict__ off,
        const float* __restrict__ msk, const __hip_bfloat16* __restrict__ A2,
        const float* __restrict__ bias, float* __restrict__ out) {

    __shared__ __align__(16) __hip_bfloat16 Bs[2][64 * 128];  // 2 x 16 KB
    __shared__ float pw[4][1024];                             // bilinear weights
    __shared__ int   pb[2][1024];                             // T elem offsets

    const int t   = threadIdx.x;
    const int bid = blockIdx.x;
    const int b   = bid & 7;               // batch<->XCD pinning (488 % 8 == 0)
    const int ho  = bid >> 3;

    // ---- phase 0: exact per-(pixel,tap) bilinear params -> LDS (1024 pairs) ----
    #pragma unroll
    for (int ii = 0; ii < 2; ++ii) {
        const int idx = ii * 512 + t;      // = k*64 + px
        const int px  = idx & 63;
        const int k   = idx >> 6;
        const bool pvalid = (px < WO);
        const int wo_c = pvalid ? px : (WO - 1);
        const int r    = ho * WO + wo_c;
        const int ki = k >> 2, kj = k & 3;
        const size_t offb = (size_t)b * (2 * K_ * HW_);
        float dy = off[offb + (size_t)(2 * k)     * HW_ + r];
        float dx = off[offb + (size_t)(2 * k + 1) * HW_ + r];
        float mm = msk[(size_t)b * (K_ * HW_) + (size_t)k * HW_ + r];
        if (!pvalid) mm = 0.0f;

        float y   = dy + (float)(ki + ho);
        float x   = dx + (float)(kj + wo_c);
        float y0f = floorf(y), x0f = floorf(x);
        float wy  = y - y0f,   wx  = x - x0f;
        int y0 = (int)y0f, x0 = (int)x0f;
        int y1 = y0 + 1,   x1 = x0 + 1;

        float wy0v = (1.0f - wy) * ((y0 >= 0 && y0 < H_) ? mm : 0.0f);
        float wy1v = wy          * ((y1 >= 0 && y1 < H_) ? mm : 0.0f);
        int cy0 = min(max(y0, 0), H_ - 1), cy1 = min(max(y1, 0), H_ - 1);

        float wx0v = (1.0f - wx) * ((x0 >= 0 && x0 < W_) ? 1.0f : 0.0f);
        float wx1v = wx          * ((x1 >= 0 && x1 < W_) ? 1.0f : 0.0f);
        int xb = min(max(x0, 0), W_ - 2);
        int tsh = x0 - xb;                 // -1,0,1 (else both x-weights 0)
        float a0 = (tsh == 0) ? wx0v : ((tsh == -1) ? wx1v : 0.0f);
        float a1 = (tsh == 0) ? wx1v : ((tsh ==  1) ? wx0v : 0.0f);

        pw[0][idx] = wy0v * a0;  pw[1][idx] = wy0v * a1;
        pw[2][idx] = wy1v * a0;  pw[3][idx] = wy1v * a1;
        pb[0][idx] = (cy0 * W_ + xb) << 7; // *128 channels (bf16 elems)
        pb[1][idx] = (cy1 * W_ + xb) << 7;
    }
    __syncthreads();

    const int lane = t & 63;
    const int wv   = t >> 6;               // 0..7 = cout-block
    const int p_g  = lane >> 2;            // gather pair-pixel within px-group
    const int mrow = lane & 15;            // MFMA pixel col
    const int quad = lane >> 4;
    const __hip_bfloat16* Tb = T + ((size_t)b << 19);

    // this wave's 2 gather units per phase: u = 2*wv + i -> (px-group, ch-group)
    int rowU[2], cbU[2];
    #pragma unroll
    for (int i = 0; i < 2; ++i) {
        const int u = (wv << 1) + i;
        rowU[i] = ((u >> 2) << 4) + p_g;               // px = pg*16 + p_g
        cbU[i]  = ((u & 3) << 5) + ((lane & 3) << 3);  // ch base 0..127
    }

    f32x4 accA = {0.f,0.f,0.f,0.f}, accB = {0.f,0.f,0.f,0.f};
    f32x4 accC = {0.f,0.f,0.f,0.f}, accD = {0.f,0.f,0.f,0.f};

    bf16x8 cU[2][4];                       // 2 units x 4 corners
    float  wtU[2][4];
    int    swzU[2];

    // gather 2 units for tap qp: 8 coalesced dwordx4 (one 64B line each)
    auto uget = [&](int qp) {
        #pragma unroll
        for (int i = 0; i < 2; ++i) {
            const int pidx = (qp << 6) + rowU[i];
            wtU[i][0] = pw[0][pidx]; wtU[i][1] = pw[1][pidx];
            wtU[i][2] = pw[2][pidx]; wtU[i][3] = pw[3][pidx];
            const __hip_bfloat16* p0 = Tb + pb[0][pidx] + cbU[i];
            const __hip_bfloat16* p1 = Tb + pb[1][pidx] + cbU[i];
            cU[i][0] = *(const bf16x8*)(const void*)(p0);          // (y0,x0)
            cU[i][1] = *(const bf16x8*)(const void*)(p0 + 128);    // (y0,x1)
            cU[i][2] = *(const bf16x8*)(const void*)(p1);          // (y1,x0)
            cU[i][3] = *(const bf16x8*)(const void*)(p1 + 128);    // (y1,x1)
            swzU[i] = (rowU[i] << 7) + ((cbU[i] + (rowU[i] << 3)) & 127);
        }
    };

    // combine (bf16 corners -> f32 bilinear -> bf16) -> 2 x ds_write_b128
    auto ucomb = [&](int bb_) {
        #pragma unroll
        for (int i = 0; i < 2; ++i) {
            bf16x8 v;
            #pragma unroll
            for (int q = 0; q < 8; ++q) {
                float s = wtU[i][0] * B2F(cU[i][0][q]) + wtU[i][1] * B2F(cU[i][1][q])
                        + wtU[i][2] * B2F(cU[i][2][q]) + wtU[i][3] * B2F(cU[i][3][q]);
                __hip_bfloat16 hh = __float2bfloat16(s);
                v[q] = *reinterpret_cast<const short*>(&hh);
            }
            *(bf16x8*)(void*)(&Bs[bb_][swzU[i]]) = v;
        }
    };

    // A-fragments for one tap (4 x bf16x8 = 16 VGPR), cout-block = wv
    bf16x8 avR[4];
    auto loadA = [&](int qp) {
        #pragma unroll
        for (int s_ = 0; s_ < 4; ++s_) {
            avR[s_] = *(const bf16x8*)(const void*)(
                A2 + ((size_t)((wv * 64 + qp * 4 + s_) * 64 + lane) << 3));
        }
    };

    auto mfma_exec = [&](int qp) {
        const int bb_ = qp & 1;
        #pragma unroll
        for (int s_ = 0; s_ < 4; ++s_) {
            const int base = (s_ << 5) + (quad << 3);
            const int r0 = mrow,      i0 = (r0 << 7) + ((base + (r0 << 3)) & 127);
            const int r1 = 16 + mrow, i1 = (r1 << 7) + ((base + (r1 << 3)) & 127);
            const int r2 = 32 + mrow, i2 = (r2 << 7) + ((base + (r2 << 3)) & 127);
            const int r3 = 48 + mrow, i3 = (r3 << 7) + ((base + (r3 << 3)) & 127);
            bf16x8 b0 = *(const bf16x8*)(const void*)(&Bs[bb_][i0]);
            bf16x8 b1 = *(const bf16x8*)(const void*)(&Bs[bb_][i1]);
            bf16x8 b2 = *(const bf16x8*)(const void*)(&Bs[bb_][i2]);
            bf16x8 b3 = *(const bf16x8*)(const void*)(&Bs[bb_][i3]);
            accA = __builtin_amdgcn_mfma_f32_16x16x32_bf16(avR[s_], b0, accA, 0, 0, 0);
            accB = __builtin_amdgcn_mfma_f32_16x16x32_bf16(avR[s_], b1, accB, 0, 0, 0);
            accC = __builtin_amdgcn_mfma_f32_16x16x32_bf16(avR[s_], b2, accC, 0, 0, 0);
            accD = __builtin_amdgcn_mfma_f32_16x16x32_bf16(avR[s_], b3, accD, 0, 0, 0);
        }
    };

    // prologue: tap 0 (the one uncovered gather stall)
    uget(0);
    ucomb(0);
    loadA(0);
    __syncthreads();

    #pragma unroll 1
    for (int qp = 1; qp < 16; ++qp) {
        uget(qp);                          // 8 gather loads, issued first
        __builtin_amdgcn_s_setprio(1);
        mfma_exec(qp - 1);                 // covers gather latency; avR ready
        __builtin_amdgcn_s_setprio(0);
        loadA(qp);                         // refills avR; covered to next phase
        ucomb(qp & 1);                     // waits gathers (already covered)
        __syncthreads();                   // one barrier per tap
    }
    mfma_exec(15);

    // ---- epilogue: C/D col = mrow (pixel), row = quad*4 + jj (cout) ----
    #pragma unroll
    for (int pg = 0; pg < 4; ++pg) {
        const int px = (pg << 4) + mrow;
        if (px < WO) {
            const size_t outb = (size_t)b * (COUT * HW_) + (size_t)(ho * WO + px);
            const f32x4 a = (pg == 0) ? accA : (pg == 1) ? accB
                          : (pg == 2) ? accC : accD;
            #pragma unroll
            for (int jj = 0; jj < 4; ++jj) {
                const int o = wv * 16 + quad * 4 + jj;
                out[outb + (size_t)o * HW_] = a[jj] + bias[o];
            }
        }
    }
}

extern "C" void kernel_launch(void* const* d_in, const int* in_sizes, int n_in,
                              void* d_out, int out_size, void* d_ws, size_t ws_size,
                              hipStream_t stream) {
    const float* inp  = (const float*)d_in[0];
    const float* off  = (const float*)d_in[1];
    const float* msk  = (const float*)d_in[2];
    const float* wgt  = (const float*)d_in[3];
    const float* bias = (const float*)d_in[4];
    float* out = (float*)d_out;

    __hip_bfloat16* A2 = (__hip_bfloat16*)d_ws;                       // 512 KB
    __hip_bfloat16* T  = (__hip_bfloat16*)((char*)d_ws + (1 << 20));  // 8 MB

    prep_all<<<640, 256, 0, stream>>>(inp, wgt, T, A2);

    int nblk = B_ * HO;                    // 488, bid&7 = batch
    deform_gather<<<nblk, 512, 0, stream>>>(T, off, msk, A2, bias, out);
}